// Round 8
// baseline (196.970 us; speedup 1.0000x reference)
//
#include <hip/hip_runtime.h>
#include <hip/hip_bf16.h>

// x [B=4][C=256][N=4096] fp32 -> attention [B][N][N] fp32 (row softmax of cosine sim)
#define BATCH 4
#define CDIM  256
#define NTOK  4096

#define BM 64      // rows per block
#define BN 128     // tokens per chunk; chunk = 128 tok x K=256 = 64 KB, double-buffered

typedef short bf16x8 __attribute__((ext_vector_type(8)));
typedef unsigned short u16x8 __attribute__((ext_vector_type(8)));
typedef float floatx4 __attribute__((ext_vector_type(4)));
typedef unsigned int uintx4 __attribute__((ext_vector_type(4)));
typedef unsigned int u32;

// Opaque def: keeps A-fragments live in VGPRs (no sink/remat into the loop).
#define PIN(v) asm volatile("" : "+v"(v))

__device__ inline u32 f2bf1(float f) {
    u32 u = __float_as_uint(f);
    u += 0x7fffu + ((u >> 16) & 1u);   // RTNE
    return u >> 16;
}
__device__ inline u32 f2bf2(float lo, float hi) { return f2bf1(lo) | (f2bf1(hi) << 16); }

__device__ inline void gload_lds16(const short* g, short* l) {
    __builtin_amdgcn_global_load_lds(
        (const __attribute__((address_space(1))) u32*)g,
        (__attribute__((address_space(3))) u32*)l, 16, 0, 0);
}

// ---------- prep: x [B][C][N] f32 -> xn [B][N][C] bf16, rows normalized to unit L2 ----------
#define TT 32
__global__ __launch_bounds__(256) void prep_kernel(const float* __restrict__ x,
                                                   short* __restrict__ xn) {
    __shared__ float tile[TT][CDIM + 2];
    __shared__ float part[8][TT];
    __shared__ float rinv_s[TT];
    const int tid = threadIdx.x;
    const int blk = blockIdx.x;            // 0..511
    const int b = blk >> 7;
    const int t0 = (blk & 127) * TT;
    const float* xb = x + (size_t)b * CDIM * NTOK;
    const int ti = tid & 31, cq = tid >> 5;
    float ss = 0.f;
    for (int c = cq; c < CDIM; c += 8) {
        float v = xb[(size_t)c * NTOK + t0 + ti];
        tile[ti][c] = v;
        ss += v * v;
    }
    part[cq][ti] = ss;
    __syncthreads();
    if (tid < TT) {
        float s = 0.f;
#pragma unroll
        for (int q = 0; q < 8; ++q) s += part[q][tid];
        rinv_s[tid] = 1.0f / sqrtf(s);
    }
    __syncthreads();
    const int tok = tid >> 3, seg = tid & 7;
    const float ri = rinv_s[tok];
    size_t obase = ((size_t)(b * NTOK + t0 + tok)) * CDIM + seg * 32;
#pragma unroll
    for (int j = 0; j < 4; ++j) {
        u32 w[4];
#pragma unroll
        for (int u = 0; u < 4; ++u) {
            float f0 = tile[tok][seg * 32 + j * 8 + 2 * u] * ri;
            float f1 = tile[tok][seg * 32 + j * 8 + 2 * u + 1] * ri;
            w[u] = f2bf2(f0, f1);
        }
        *(uintx4*)&xn[obase + j * 8] = (uintx4){w[0], w[1], w[2], w[3]};
    }
}

// ---------- single-sweep GEMM + exp -> bf16 tiled scratch + per-row rinv ----------
// Block: 64 rows x 4096 cols, K=256, 8 waves (2 row x 4 col). A pinned in regs.
// B chunk = 128 tok x 256 k as 4 sub-chunks [128][64], XOR swizzle
// (16B-pos p of row tr holds logical chunk p ^ (tr&7)). Double buffer,
// stage(ct+1) issued before compute(ct); one __syncthreads per chunk.
// Output: scratch[D][ct][64][128] bf16 (cached stores into a hot 16-KB tile),
// rowsum accumulated from the ROUNDED values; rinvG[row] written at the end.
__global__ __launch_bounds__(512, 2) void exp_kernel(const short* __restrict__ xn,
                                                     unsigned short* __restrict__ sc,
                                                     float* __restrict__ rinvG) {
    __shared__ short Bs[2][4][128][64];      // 2 x 64 KB
    __shared__ float rowsumLds[BM][4];
    const int tid = threadIdx.x;
    const int D = blockIdx.x;                // natural order (proven L2 coherence)
    const int b = D >> 6;
    const int rb = (D & 63) * BM;
    const short* xnb = xn + (size_t)b * NTOK * CDIM;
    const int lane = tid & 63, wid = tid >> 6;     // 8 waves: 2 row x 4 col
    const int wr = (wid >> 2) * 32;                // 0 / 32
    const int wc = (wid & 3) * 32;                 // 0 / 32 / 64 / 96
    const int r0 = lane & 15, kq = lane >> 4;

    // staging roles (per wave): rows wid*8 .. wid*8+7 (+64 for h=1)
    const int trl0 = (wid << 3) + (lane >> 3);     // 0..63
    const int c8 = (lane & 7) ^ (lane >> 3);       // inverse-swizzled source 16B-chunk

    // A fragments: rows rb + wr + m*16 + r0, full K=256 in registers, PINNED
    bf16x8 afr[2][8];
#pragma unroll
    for (int m = 0; m < 2; ++m) {
        const short* arow = xnb + (size_t)(rb + wr + m * 16 + r0) * CDIM;
#pragma unroll
        for (int j = 0; j < 8; ++j) {
            afr[m][j] = *(const bf16x8*)(arow + j * 32 + kq * 8);
            PIN(afr[m][j]);
        }
    }

    float psum[2][4] = {{0.f,0.f,0.f,0.f},{0.f,0.f,0.f,0.f}};

    auto stage = [&](int ct, int buf) {
        const short* srcBase = xnb + (size_t)(ct * BN) * CDIM;
#pragma unroll
        for (int kc = 0; kc < 4; ++kc)
#pragma unroll
            for (int h = 0; h < 2; ++h) {
                const short* s = srcBase + (size_t)(h * 64 + trl0) * CDIM + kc * 64 + c8 * 8;
                gload_lds16(s, &Bs[buf][kc][h * 64 + (wid << 3)][0]);
            }
    };

    stage(0, 0);
    __syncthreads();                      // buffer 0 ready

    for (int ct = 0; ct < 32; ++ct) {
        const int cur = ct & 1;
        if (ct + 1 < 32) stage(ct + 1, cur ^ 1);   // flies during compute

        floatx4 acc[2][2];
#pragma unroll
        for (int m = 0; m < 2; ++m)
#pragma unroll
            for (int n = 0; n < 2; ++n)
                acc[m][n] = (floatx4){0.f, 0.f, 0.f, 0.f};

        __builtin_amdgcn_s_setprio(1);
#pragma unroll
        for (int kc = 0; kc < 4; ++kc) {
#pragma unroll
            for (int kk = 0; kk < 2; ++kk) {
                bf16x8 bfr[2];
#pragma unroll
                for (int n = 0; n < 2; ++n) {
                    const int tr = wc + n * 16 + r0;
                    const int p = ((kk << 2) | kq) ^ (tr & 7);
                    bfr[n] = *(const bf16x8*)&Bs[cur][kc][tr][p * 8];
                }
                acc[0][0] = __builtin_amdgcn_mfma_f32_16x16x32_bf16(afr[0][kc*2+kk], bfr[0], acc[0][0], 0,0,0);
                acc[1][0] = __builtin_amdgcn_mfma_f32_16x16x32_bf16(afr[1][kc*2+kk], bfr[0], acc[1][0], 0,0,0);
                acc[0][1] = __builtin_amdgcn_mfma_f32_16x16x32_bf16(afr[0][kc*2+kk], bfr[1], acc[0][1], 0,0,0);
                acc[1][1] = __builtin_amdgcn_mfma_f32_16x16x32_bf16(afr[1][kc*2+kk], bfr[1], acc[1][1], 0,0,0);
            }
        }
        __builtin_amdgcn_s_setprio(0);

        // epilogue: exp, round to bf16, store to hot 16-KB tile (cached),
        // accumulate rowsum from the ROUNDED values.
        {
            unsigned short* tileBase = sc + (((size_t)(D * 32 + ct)) << 13);
#pragma unroll
            for (int m = 0; m < 2; ++m)
#pragma unroll
                for (int r = 0; r < 4; ++r) {
                    const int rowl = wr + m * 16 + kq * 4 + r;
#pragma unroll
                    for (int n = 0; n < 2; ++n) {
                        float e = __expf(acc[m][n][r] - 1.f);
                        u32 h = f2bf1(e);
                        tileBase[rowl * 128 + wc + n * 16 + r0] = (unsigned short)h;
                        psum[m][r] += __uint_as_float(h << 16);
                    }
                }
        }
        __syncthreads();                  // stage(ct+1) drained; buffer swap safe
    } // ct

    // block-level rowsum -> rinv
#pragma unroll
    for (int m = 0; m < 2; ++m)
#pragma unroll
        for (int r = 0; r < 4; ++r) {
            float v = psum[m][r];
            v += __shfl_xor(v, 1);
            v += __shfl_xor(v, 2);
            v += __shfl_xor(v, 4);
            v += __shfl_xor(v, 8);
            if (r0 == 0) rowsumLds[wr + m * 16 + kq * 4 + r][wid & 3] = v;
        }
    __syncthreads();
    if (tid < BM) {
        float s = rowsumLds[tid][0] + rowsumLds[tid][1] +
                  rowsumLds[tid][2] + rowsumLds[tid][3];
        rinvG[b * NTOK + rb + tid] = 1.0f / s;
    }
}

// ---------- rescale: bf16 tiled scratch -> fp32 linear out, streaming writes ----------
// One wave per row (16384 rows, 4096 blocks x 4 waves). Per iter: lane reads 16 B
// from its tile (contiguous 256-B segments per 16-lane group), writes 32 B of a
// 2-KB contiguous per-wave nontemporal stream; rows sequential -> page-friendly.
__global__ __launch_bounds__(256) void rescale_kernel(const unsigned short* __restrict__ sc,
                                                      const float* __restrict__ rinvG,
                                                      float* __restrict__ out) {
    const int row = (blockIdx.x << 2) + (threadIdx.x >> 6);   // 0..16383
    const int lane = threadIdx.x & 63;
    const int rr = row & (NTOK - 1);
    const int D = ((row >> 12) << 6) + (rr >> 6);             // producing block
    const float ri = rinvG[row];
    float* orow = out + ((size_t)row << 12);
#pragma unroll
    for (int it = 0; it < 8; ++it) {
        const int col = (it << 9) + (lane << 3);
        const int ct = col >> 7;
        const unsigned short* p = sc + (((size_t)(D * 32 + ct)) << 13)
                                + ((rr & 63) << 7) + (col & 127);
        u16x8 v = *(const u16x8*)p;
        floatx4 o0, o1;
#pragma unroll
        for (int j = 0; j < 4; ++j) {
            o0[j] = __uint_as_float(((u32)v[j]) << 16) * ri;
            o1[j] = __uint_as_float(((u32)v[4 + j]) << 16) * ri;
        }
        __builtin_nontemporal_store(o0, (floatx4*)&orow[col]);
        __builtin_nontemporal_store(o1, (floatx4*)&orow[col + 4]);
    }
}

extern "C" void kernel_launch(void* const* d_in, const int* in_sizes, int n_in,
                              void* d_out, int out_size, void* d_ws, size_t ws_size,
                              hipStream_t stream) {
    const float* x = (const float*)d_in[0];
    float* out = (float*)d_out;
    char* ws = (char*)d_ws;
    short* xn = (short*)ws;                                   // 8 MB  [B][N][C] bf16
    float* rinvG = (float*)(ws + (8u << 20));                 // 64 KB [B*N] fp32
    unsigned short* sc = (unsigned short*)(ws + (16u << 20)); // 134 MB [256][32][64][128] bf16

    prep_kernel<<<BATCH * (NTOK / TT), 256, 0, stream>>>(x, xn);
    exp_kernel<<<NTOK / BM * BATCH, 512, 0, stream>>>(xn, sc, rinvG);
    rescale_kernel<<<(BATCH * NTOK) / 4, 256, 0, stream>>>(sc, rinvG, out);
}

// Round 9
// 143.794 us; speedup vs baseline: 1.3698x; 1.3698x over previous
//
#include <hip/hip_runtime.h>
#include <hip/hip_bf16.h>

// x [B=4][C=256][N=4096] fp32 -> attention [B][N][N] fp32 (row softmax of cosine sim)
#define BATCH 4
#define CDIM  256
#define NTOK  4096

#define BM 64      // rows per block
#define BN 128     // tokens per ct tile; staged as 4 sub-chunks of 128 tok x 64 k (16 KB)

typedef short bf16x8 __attribute__((ext_vector_type(8)));
typedef float floatx4 __attribute__((ext_vector_type(4)));
typedef unsigned int uintx4 __attribute__((ext_vector_type(4)));
typedef unsigned int u32;

#define PIN(v) asm volatile("" : "+v"(v))
#define WAIT(n) asm volatile("s_waitcnt vmcnt(" #n ")" ::: "memory")
#define BAR() do { __builtin_amdgcn_s_barrier(); asm volatile("" ::: "memory"); } while (0)

__device__ inline u32 f2bf1(float f) {
    u32 u = __float_as_uint(f);
    u += 0x7fffu + ((u >> 16) & 1u);   // RTNE
    return u >> 16;
}
__device__ inline u32 f2bf2(float lo, float hi) { return f2bf1(lo) | (f2bf1(hi) << 16); }

__device__ inline void gload_lds16(const short* g, short* l) {
    __builtin_amdgcn_global_load_lds(
        (const __attribute__((address_space(1))) u32*)g,
        (__attribute__((address_space(3))) u32*)l, 16, 0, 0);
}

// ---------- prep: x [B][C][N] f32 -> xn [B][N][C] bf16, rows normalized to unit L2 ----------
#define TT 32
__global__ __launch_bounds__(256) void prep_kernel(const float* __restrict__ x,
                                                   short* __restrict__ xn) {
    __shared__ float tile[TT][CDIM + 2];
    __shared__ float part[8][TT];
    __shared__ float rinv_s[TT];
    const int tid = threadIdx.x;
    const int blk = blockIdx.x;            // 0..511
    const int b = blk >> 7;
    const int t0 = (blk & 127) * TT;
    const float* xb = x + (size_t)b * CDIM * NTOK;
    const int ti = tid & 31, cq = tid >> 5;
    float ss = 0.f;
    for (int c = cq; c < CDIM; c += 8) {
        float v = xb[(size_t)c * NTOK + t0 + ti];
        tile[ti][c] = v;
        ss += v * v;
    }
    part[cq][ti] = ss;
    __syncthreads();
    if (tid < TT) {
        float s = 0.f;
#pragma unroll
        for (int q = 0; q < 8; ++q) s += part[q][tid];
        rinv_s[tid] = 1.0f / sqrtf(s);
    }
    __syncthreads();
    const int tok = tid >> 3, seg = tid & 7;
    const float ri = rinv_s[tok];
    size_t obase = ((size_t)(b * NTOK + t0 + tok)) * CDIM + seg * 32;
#pragma unroll
    for (int j = 0; j < 4; ++j) {
        u32 w[4];
#pragma unroll
        for (int u = 0; u < 4; ++u) {
            float f0 = tile[tok][seg * 32 + j * 8 + 2 * u] * ri;
            float f1 = tile[tok][seg * 32 + j * 8 + 2 * u + 1] * ri;
            w[u] = f2bf2(f0, f1);
        }
        *(uintx4*)&xn[obase + j * 8] = (uintx4){w[0], w[1], w[2], w[3]};
    }
}

// ---------- fused two-sweep GEMM + softmax, counted-vmcnt 4-deep ring ----------
// Block: 64 rows x 4096 cols, K=256, 8 waves (2 row x 4 col). A pinned in regs.
// Sub-chunk t = 4*ct + kc = 128 tok x 64 k (16 KB) in ring buffer Bs[kc] (index
// STATIC since kc unrolled). Prefetch depth 2; counted vmcnt (4 / 12-with-stores);
// raw s_barrier per sub-chunk. XOR swizzle: 16B-pos p of row tr holds p^(tr&7).
__global__ __launch_bounds__(512, 2) void attn_kernel(const short* __restrict__ xn,
                                                      float* __restrict__ out) {
    __shared__ short Bs[4][128][64];      // 4 x 16 KB ring
    __shared__ float rowsumLds[BM][4];
    const int tid = threadIdx.x;
    const int D = blockIdx.x;
    const int b = D >> 6;
    const int rb = (D & 63) * BM;
    const short* xnb = xn + (size_t)b * NTOK * CDIM;
    float* outb = out + ((size_t)b << 24);
    const int lane = tid & 63, wid = tid >> 6;     // 8 waves: 2 row x 4 col
    const int wr = (wid >> 2) * 32;
    const int wc = (wid & 3) * 32;
    const int r0 = lane & 15, kq = lane >> 4;
    const int sx = r0 & 7;                         // tr & 7 for both n-tiles
    const int tr0 = wc + r0, tr1 = wc + 16 + r0;

    // staging roles (per wave): rows wid*8..+7 (and +64)
    const int trl0 = (wid << 3) + (lane >> 3);
    const int c8 = (lane & 7) ^ (lane >> 3);       // inverse-swizzled source 16B-chunk

    // A fragments: rows rb + wr + m*16 + r0, full K=256 in registers, PINNED
    bf16x8 afr[2][8];
#pragma unroll
    for (int m = 0; m < 2; ++m) {
        const short* arow = xnb + (size_t)(rb + wr + m * 16 + r0) * CDIM;
#pragma unroll
        for (int j = 0; j < 8; ++j) {
            afr[m][j] = *(const bf16x8*)(arow + j * 32 + kq * 8);
            PIN(afr[m][j]);
        }
    }

    float psum0[4] = {0.f, 0.f, 0.f, 0.f}, psum1[4] = {0.f, 0.f, 0.f, 0.f};
    float rinv0[4], rinv1[4];
    floatx4 acc00, acc01, acc10, acc11;

    // stage sub-chunk (ct, kc) into ring slot kc: 2 gloads per thread
    auto stage = [&](int ct, int kc) {
        const short* s0 = xnb + (size_t)(ct * BN + trl0) * CDIM + kc * 64 + c8 * 8;
        short* d = &Bs[kc][wid << 3][0];
        gload_lds16(s0, d);
        gload_lds16(s0 + (size_t)64 * CDIM, d + 64 * 64);
    };

#define ACCZERO() do { acc00 = (floatx4){0,0,0,0}; acc01 = (floatx4){0,0,0,0}; \
                       acc10 = (floatx4){0,0,0,0}; acc11 = (floatx4){0,0,0,0}; } while (0)

#define COMPUTE(KC) do { \
    __builtin_amdgcn_s_setprio(1); \
    const int p0 = kq ^ sx, p1 = (4 | kq) ^ sx; \
    bf16x8 b0a = *(const bf16x8*)&Bs[KC][tr0][p0 * 8]; \
    bf16x8 b1a = *(const bf16x8*)&Bs[KC][tr1][p0 * 8]; \
    bf16x8 b0b = *(const bf16x8*)&Bs[KC][tr0][p1 * 8]; \
    bf16x8 b1b = *(const bf16x8*)&Bs[KC][tr1][p1 * 8]; \
    acc00 = __builtin_amdgcn_mfma_f32_16x16x32_bf16(afr[0][(KC)*2],   b0a, acc00, 0,0,0); \
    acc10 = __builtin_amdgcn_mfma_f32_16x16x32_bf16(afr[1][(KC)*2],   b0a, acc10, 0,0,0); \
    acc01 = __builtin_amdgcn_mfma_f32_16x16x32_bf16(afr[0][(KC)*2],   b1a, acc01, 0,0,0); \
    acc11 = __builtin_amdgcn_mfma_f32_16x16x32_bf16(afr[1][(KC)*2],   b1a, acc11, 0,0,0); \
    acc00 = __builtin_amdgcn_mfma_f32_16x16x32_bf16(afr[0][(KC)*2+1], b0b, acc00, 0,0,0); \
    acc10 = __builtin_amdgcn_mfma_f32_16x16x32_bf16(afr[1][(KC)*2+1], b0b, acc10, 0,0,0); \
    acc01 = __builtin_amdgcn_mfma_f32_16x16x32_bf16(afr[0][(KC)*2+1], b1b, acc01, 0,0,0); \
    acc11 = __builtin_amdgcn_mfma_f32_16x16x32_bf16(afr[1][(KC)*2+1], b1b, acc11, 0,0,0); \
    __builtin_amdgcn_s_setprio(0); \
} while (0)

// step with prefetch-stage of (SCT,SKC), counted wait WN, then compute ring slot KC
#define STEP(KC, SCT, SKC, WN) do { stage((SCT), (SKC)); WAIT(WN); BAR(); COMPUTE(KC); } while (0)
#define STEPNS(KC, WN)        do { WAIT(WN); BAR(); COMPUTE(KC); } while (0)

#define EPI0() do { \
    _Pragma("unroll") for (int r = 0; r < 4; ++r) { \
        psum0[r] += __expf(acc00[r] - 1.f) + __expf(acc01[r] - 1.f); \
        psum1[r] += __expf(acc10[r] - 1.f) + __expf(acc11[r] - 1.f); } \
} while (0)

#define EPI1(CT) do { \
    _Pragma("unroll") for (int r = 0; r < 4; ++r) { \
        const int row_a = rb + wr + kq * 4 + r; \
        float* pa = outb + ((size_t)row_a << 12) + ((CT) << 7) + wc + r0; \
        __builtin_nontemporal_store(__expf(acc00[r] - 1.f) * rinv0[r], pa); \
        __builtin_nontemporal_store(__expf(acc01[r] - 1.f) * rinv0[r], pa + 16); \
        float* pb = pa + ((size_t)16 << 12); \
        __builtin_nontemporal_store(__expf(acc10[r] - 1.f) * rinv1[r], pb); \
        __builtin_nontemporal_store(__expf(acc11[r] - 1.f) * rinv1[r], pb + 16); } \
} while (0)

    // ================= sweep 0: rowsums =================
    stage(0, 0); stage(0, 1);
    for (int ct = 0; ct < 31; ++ct) {
        ACCZERO();
        STEP(0, ct, 2, 4);
        STEP(1, ct, 3, 4);
        STEP(2, ct + 1, 0, 4);
        STEP(3, ct + 1, 1, 4);
        EPI0();
    }
    ACCZERO();
    STEP(0, 31, 2, 4);
    STEP(1, 31, 3, 4);
    STEPNS(2, 2);
    STEPNS(3, 0);
    EPI0();

    // rowsum reduce -> rinv
#pragma unroll
    for (int r = 0; r < 4; ++r) {
        float v0 = psum0[r], v1 = psum1[r];
        v0 += __shfl_xor(v0, 1); v0 += __shfl_xor(v0, 2);
        v0 += __shfl_xor(v0, 4); v0 += __shfl_xor(v0, 8);
        v1 += __shfl_xor(v1, 1); v1 += __shfl_xor(v1, 2);
        v1 += __shfl_xor(v1, 4); v1 += __shfl_xor(v1, 8);
        if (r0 == 0) {
            rowsumLds[wr + kq * 4 + r][wid & 3] = v0;
            rowsumLds[wr + 16 + kq * 4 + r][wid & 3] = v1;
        }
    }
    __syncthreads();
#pragma unroll
    for (int r = 0; r < 4; ++r) {
        const int ra = wr + kq * 4 + r, rbw = wr + 16 + kq * 4 + r;
        rinv0[r] = 1.0f / (rowsumLds[ra][0] + rowsumLds[ra][1] + rowsumLds[ra][2] + rowsumLds[ra][3]);
        rinv1[r] = 1.0f / (rowsumLds[rbw][0] + rowsumLds[rbw][1] + rowsumLds[rbw][2] + rowsumLds[rbw][3]);
    }
    __syncthreads();   // also guards ring reuse below

    // ================= sweep 1: normalized stores =================
    stage(0, 0); stage(0, 1);
    {   // ct = 0 peeled (no stores outstanding yet -> waits of 4)
        ACCZERO();
        STEP(0, 0, 2, 4);
        STEP(1, 0, 3, 4);
        STEP(2, 1, 0, 4);
        STEP(3, 1, 1, 4);
        EPI1(0);
    }
    for (int ct = 1; ct < 31; ++ct) {
        ACCZERO();
        STEP(0, ct, 2, 12);      // 8 stores of ct-1 sit between counted loads
        STEP(1, ct, 3, 12);
        STEP(2, ct + 1, 0, 4);
        STEP(3, ct + 1, 1, 4);
        EPI1(ct);
    }
    ACCZERO();
    STEP(0, 31, 2, 12);
    STEP(1, 31, 3, 12);
    STEPNS(2, 2);
    STEPNS(3, 0);
    EPI1(31);

#undef ACCZERO
#undef COMPUTE
#undef STEP
#undef STEPNS
#undef EPI0
#undef EPI1
}

extern "C" void kernel_launch(void* const* d_in, const int* in_sizes, int n_in,
                              void* d_out, int out_size, void* d_ws, size_t ws_size,
                              hipStream_t stream) {
    const float* x = (const float*)d_in[0];
    float* out = (float*)d_out;
    short* xn = (short*)d_ws;    // [B][N][C] bf16 = 8 MB

    prep_kernel<<<BATCH * (NTOK / TT), 256, 0, stream>>>(x, xn);
    attn_kernel<<<NTOK / BM * BATCH, 512, 0, stream>>>(xn, out);
}